// Round 1
// baseline (496.398 us; speedup 1.0000x reference)
//
#include <hip/hip_runtime.h>

// Problem constants (from reference)
constexpr int B_ = 64;
constexpr int L_ = 128;
constexpr int R_ = 1024;
constexpr int M_ = 4194304;
constexpr int K_ = 10;
#define HALF_LOG_2PI 0.9189385332046727f  // 0.5*log(2*pi)

// Each thread processes 2 consecutive m's => 80-byte (16B-aligned) rows per array.
__global__ __launch_bounds__(256) void mdn_loss_kernel(
    const float* __restrict__ pos1,    // [64,128,3]
    const float* __restrict__ pos2,    // [64,1024,3]
    const float* __restrict__ logpi,   // [M,K]
    const float* __restrict__ sigma,   // [M,K]
    const float* __restrict__ mu,      // [M,K]
    const int*   __restrict__ mdn_idx, // [M]
    double*      __restrict__ acc)     // [1] accumulator (pre-zeroed)
{
    const int t = blockIdx.x * blockDim.x + threadIdx.x;   // t in [0, M/2)

    // ---- vectorized loads: 5x float4 per array (20 floats = 2 rows of K=10) ----
    float lp[20], sg[20], muv[20];
    {
        const float4* lp4 = reinterpret_cast<const float4*>(logpi) + 5 * t;
        const float4* sg4 = reinterpret_cast<const float4*>(sigma) + 5 * t;
        const float4* mu4 = reinterpret_cast<const float4*>(mu)    + 5 * t;
#pragma unroll
        for (int i = 0; i < 5; ++i) {
            float4 a = lp4[i];
            lp[4*i+0] = a.x; lp[4*i+1] = a.y; lp[4*i+2] = a.z; lp[4*i+3] = a.w;
            float4 b = sg4[i];
            sg[4*i+0] = b.x; sg[4*i+1] = b.y; sg[4*i+2] = b.z; sg[4*i+3] = b.w;
            float4 c = mu4[i];
            muv[4*i+0] = c.x; muv[4*i+1] = c.y; muv[4*i+2] = c.z; muv[4*i+3] = c.w;
        }
    }
    const int2 idx2 = *(reinterpret_cast<const int2*>(mdn_idx) + t);

    float local = 0.0f;
#pragma unroll
    for (int h = 0; h < 2; ++h) {
        const int idx = (h == 0) ? idx2.x : idx2.y;
        // decode: b = idx >> 17, l = (idx >> 10) & 127, r = idx & 1023
        const int b = idx >> 17;
        const int l = (idx >> 10) & (L_ - 1);
        const int r = idx & (R_ - 1);
        const float* p1 = pos1 + (b * L_ + l) * 3;
        const float* p2 = pos2 + (b * R_ + r) * 3;
        const float dx = p1[0] - p2[0];
        const float dy = p1[1] - p2[1];
        const float dz = p1[2] - p2[2];
        const float dist = sqrtf(dx*dx + dy*dy + dz*dz);

        const int base = 10 * h;
        float term[K_];
        float mx = -INFINITY;
#pragma unroll
        for (int k = 0; k < K_; ++k) {
            const float s  = sg[base + k];
            const float z  = (dist - muv[base + k]) / s;
            const float tt = lp[base + k] - 0.5f * z * z - __logf(s);
            term[k] = tt;
            mx = fmaxf(mx, tt);
        }
        float ssum = 0.0f;
#pragma unroll
        for (int k = 0; k < K_; ++k) ssum += __expf(term[k] - mx);
        // loss = -(lse - HALF_LOG_2PI) = HALF_LOG_2PI - mx - log(ssum)
        local += HALF_LOG_2PI - mx - __logf(ssum);
    }

    // ---- reduction: wave shuffle -> LDS across 4 waves -> one double atomic ----
#pragma unroll
    for (int off = 32; off > 0; off >>= 1)
        local += __shfl_down(local, off, 64);

    __shared__ float wsum[4];
    const int lane = threadIdx.x & 63;
    const int wid  = threadIdx.x >> 6;
    if (lane == 0) wsum[wid] = local;
    __syncthreads();
    if (threadIdx.x == 0) {
        const float blk = wsum[0] + wsum[1] + wsum[2] + wsum[3];
        atomicAdd(acc, (double)blk);
    }
}

__global__ void finalize_kernel(const double* __restrict__ acc, float* __restrict__ out)
{
    out[0] = (float)(acc[0] / (double)M_);
}

extern "C" void kernel_launch(void* const* d_in, const int* in_sizes, int n_in,
                              void* d_out, int out_size, void* d_ws, size_t ws_size,
                              hipStream_t stream) {
    const float* pos1    = (const float*)d_in[0];
    const float* pos2    = (const float*)d_in[1];
    const float* logpi   = (const float*)d_in[2];
    const float* sigma   = (const float*)d_in[3];
    const float* mu      = (const float*)d_in[4];
    const int*   mdn_idx = (const int*)d_in[5];
    float* out = (float*)d_out;
    double* acc = (double*)d_ws;

    // zero the accumulator (d_ws is re-poisoned to 0xAA before every launch)
    hipMemsetAsync(acc, 0, sizeof(double), stream);

    const int threads = 256;
    const int total_t = M_ / 2;                 // 2,097,152 threads
    const int blocks  = total_t / threads;      // 8192 blocks exactly
    mdn_loss_kernel<<<blocks, threads, 0, stream>>>(pos1, pos2, logpi, sigma, mu,
                                                    mdn_idx, acc);
    finalize_kernel<<<1, 1, 0, stream>>>(acc, out);
}